// Round 4
// baseline (146.451 us; speedup 1.0000x reference)
//
#include <hip/hip_runtime.h>
#include <math.h>

#define NB 10
#define NCLS 100
#define RPT 64          // rows per tile
#define LSTR 104        // LDS row stride in floats: 16B-aligned, <=2-way banks

// Stage 64 rows (25.6KB) to LDS with fully wave-contiguous float4 loads
// (lane i reads base + i*16B -> each 128B line touched exactly once, by one
// instruction). Compute = R3's verified 4-lane-per-row path, but from LDS.
// fp32 LDS partials -> double global atomics -> fp64 finalize (absmax 0.0 x3).
__global__ __launch_bounds__(256) void ece_main(const float* __restrict__ outputs,
                                                const int* __restrict__ targets,
                                                double* __restrict__ gacc,
                                                int nrows) {
    __shared__ float tile[RPT * LSTR];          // 26.6 KB
    __shared__ int   ttgt[RPT];
    __shared__ float s_cnt[NB], s_sp[NB], s_sc[NB];

    const int tid = threadIdx.x;
    if (tid < NB) { s_cnt[tid] = 0.f; s_sp[tid] = 0.f; s_sc[tid] = 0.f; }

    const int r_loc = tid >> 2;                 // 0..63 : row within tile
    const int q     = tid & 3;                  // quarter within row

    const int ntiles = (nrows + RPT - 1) / RPT;

    for (int ti = blockIdx.x; ti < ntiles; ti += gridDim.x) {
        const int row0 = ti * RPT;
        const int nr   = min(nrows - row0, RPT);   // rows in this tile
        const int fmax = nr * 25;                  // valid float4 count

        __syncthreads();   // previous compute done before overwriting tile
        {
            const float4* __restrict__ src =
                reinterpret_cast<const float4*>(outputs + (size_t)row0 * NCLS);
            #pragma unroll
            for (int k = 0; k < 7; ++k) {
                const int f = tid + 256 * k;       // 0..1791, need < 1600
                if (f < fmax) {
                    const float4 v = src[f];
                    const int pr = f / 25;         // row in tile
                    const int pc = (f % 25) * 4;   // col
                    *reinterpret_cast<float4*>(&tile[pr * LSTR + pc]) = v;
                }
            }
            if (tid < nr) ttgt[tid] = targets[row0 + tid];
        }
        __syncthreads();

        const int  row    = row0 + r_loc;
        const bool active = row < nrows;

        // load my quarter of the row from LDS (static indices -> VGPRs)
        const float* __restrict__ L = &tile[r_loc * LSTR];
        float4 v[6];
        #pragma unroll
        for (int k = 0; k < 6; ++k)
            v[k] = *reinterpret_cast<const float4*>(&L[q * 4 + k * 16]);
        const float tail = L[96 + q];
        const int t = ttgt[r_loc & (RPT - 1)];

        // local (max, argcol), first occurrence = lowest col wins
        float m = v[0].x;
        int   c = q * 4;
        #pragma unroll
        for (int k = 0; k < 6; ++k) {
            const int base = k * 16 + q * 4;
            if (k > 0 && v[k].x > m) { m = v[k].x; c = base; }
            if (v[k].y > m) { m = v[k].y; c = base + 1; }
            if (v[k].z > m) { m = v[k].z; c = base + 2; }
            if (v[k].w > m) { m = v[k].w; c = base + 3; }
        }
        if (tail > m) { m = tail; c = 96 + q; }

        // 4-lane group reduce (max, argcol)
        #pragma unroll
        for (int off = 1; off <= 2; off <<= 1) {
            const float om = __shfl_xor(m, off);
            const int   oc = __shfl_xor(c, off);
            if (om > m || (om == m && oc < c)) { m = om; c = oc; }
        }

        // sum of exp(x - m); grab the target element on the way
        float s = 0.f, te = 0.f;
        #pragma unroll
        for (int k = 0; k < 6; ++k) {
            const int base = k * 16 + q * 4;
            const float e0 = __expf(v[k].x - m);
            const float e1 = __expf(v[k].y - m);
            const float e2 = __expf(v[k].z - m);
            const float e3 = __expf(v[k].w - m);
            s += (e0 + e1) + (e2 + e3);
            if (base     == t) te = e0;
            if (base + 1 == t) te = e1;
            if (base + 2 == t) te = e2;
            if (base + 3 == t) te = e3;
        }
        {
            const float et = __expf(tail - m);
            s += et;
            if (96 + q == t) te = et;
        }
        #pragma unroll
        for (int off = 1; off <= 2; off <<= 1) {
            s  += __shfl_xor(s, off);
            te += __shfl_xor(te, off);
        }

        if (q == 0 && active) {
            const float p = te / s;                    // in (0, 1]
            const float corr = (c == t) ? 1.0f : 0.0f;
            const float b[NB + 1] = {0.0f, 0.1f, 0.2f, 0.3f, 0.4f, 0.5f,
                                     0.6f, 0.7f, 0.8f, 0.9f, 1.0f};
            int j = 0;
            #pragma unroll
            for (int k = 0; k <= NB; ++k) j += (b[k] < p) ? 1 : 0;
            int bin = j - 1;
            if (bin >= 0) {
                if (bin > NB - 1) bin = NB - 1;
                atomicAdd(&s_cnt[bin], 1.0f);
                atomicAdd(&s_sp[bin], p);
                atomicAdd(&s_sc[bin], corr);
            }
        }
    }

    __syncthreads();
    if (tid < NB) {
        atomicAdd(&gacc[tid],          (double)s_cnt[tid]);
        atomicAdd(&gacc[NB + tid],     (double)s_sp[tid]);
        atomicAdd(&gacc[2 * NB + tid], (double)s_sc[tid]);
    }
}

__global__ void ece_final(const double* __restrict__ gacc, float* __restrict__ out) {
    if (threadIdx.x == 0 && blockIdx.x == 0) {
        double ece = 0.0, total = 0.0;
        for (int i = 0; i < NB; ++i) {
            const double c = gacc[i];
            if (c > 0.0) {
                const double ap = gacc[NB + i] / c;
                const double ac = gacc[2 * NB + i] / c;
                ece += c * fabs(ap - ac);
                total += c;
            }
        }
        out[0] = (total > 0.0) ? (float)(ece / total) : 0.0f;
    }
}

extern "C" void kernel_launch(void* const* d_in, const int* in_sizes, int n_in,
                              void* d_out, int out_size, void* d_ws, size_t ws_size,
                              hipStream_t stream) {
    const float* outputs = (const float*)d_in[0];
    const int*   targets = (const int*)d_in[1];
    float* out   = (float*)d_out;
    double* gacc = (double*)d_ws;

    const int nrows = in_sizes[1];  // 1,000,000

    hipMemsetAsync(gacc, 0, 3 * NB * sizeof(double), stream);

    const int blocks = 2048;  // grid-stride over 15625 tiles; 6 resident/CU (LDS)
    ece_main<<<blocks, 256, 0, stream>>>(outputs, targets, gacc, nrows);
    ece_final<<<1, 64, 0, stream>>>(gacc, out);
}